// Round 9
// baseline (778.707 us; speedup 1.0000x reference)
//
#include <hip/hip_runtime.h>
#include <stdint.h>

#define E_NUM 1000000
#define NNODES 100000
#define M_TILE 64
#define NBLK 15625   // 1e6 / 64 exact

typedef __attribute__((ext_vector_type(8))) short short8;
typedef __attribute__((ext_vector_type(4))) short short4v;
typedef __attribute__((ext_vector_type(4))) float f32x4;

// ws layout (bytes)
static constexpr size_t OFF_ZU = 0;                       // 100000*128*2 = 25,600,000
static constexpr size_t OFF_ZB = 25600000;                // + 25,600,000
static constexpr size_t OFF_W1 = 51200000;                // 256*256*2 = 131072
static constexpr size_t OFF_W2 = 51200000 + 131072;
static constexpr size_t OFF_W3 = 51200000 + 262144;       // padded [16][256] bf16 = 8192

__device__ __forceinline__ uint16_t f2bf(float x) {
  union { float f; uint32_t u; } a; a.f = x;
  uint32_t r = a.u + 0x7fffu + ((a.u >> 16) & 1u);  // round-to-nearest-even
  return (uint16_t)(r >> 16);
}

__device__ __forceinline__ uint32_t pkbf(float a, float b) {
  uint32_t r;
  asm("v_cvt_pk_bf16_f32 %0, %1, %2" : "=v"(r) : "v"(a), "v"(b));
  return r;
}

__global__ void conv_z_kernel(const float* __restrict__ zu, const float* __restrict__ zb,
                              uint16_t* __restrict__ ou, uint16_t* __restrict__ ob) {
  const int64_t n4 = (int64_t)NNODES * 128 / 4;
  for (int64_t i = (int64_t)blockIdx.x * blockDim.x + threadIdx.x; i < n4;
       i += (int64_t)gridDim.x * blockDim.x) {
    float4 u = reinterpret_cast<const float4*>(zu)[i];
    float4 b = reinterpret_cast<const float4*>(zb)[i];
    short4v pu, pb;
    pu[0] = (short)f2bf(u.x); pu[1] = (short)f2bf(u.y);
    pu[2] = (short)f2bf(u.z); pu[3] = (short)f2bf(u.w);
    pb[0] = (short)f2bf(b.x); pb[1] = (short)f2bf(b.y);
    pb[2] = (short)f2bf(b.z); pb[3] = (short)f2bf(b.w);
    *reinterpret_cast<short4v*>(ou + i * 4) = pu;
    *reinterpret_cast<short4v*>(ob + i * 4) = pb;
  }
}

__global__ void conv_w_kernel(const float* __restrict__ W1, const float* __restrict__ W2,
                              const float* __restrict__ W3,
                              uint16_t* __restrict__ o1, uint16_t* __restrict__ o2,
                              uint16_t* __restrict__ o3) {
  const int i = blockIdx.x * 256 + threadIdx.x;
  if (i < 65536) {
    o1[i] = f2bf(W1[i]);
    o2[i] = f2bf(W2[i]);
  }
  if (i < 4096) {  // W3 padded [10][256] -> [16][256], zero rows
    const int r = i >> 8, c = i & 255;
    o3[i] = (r < 10) ? f2bf(W3[r * 256 + c]) : (uint16_t)0;
  }
}

// Fused MLP, non-persistent. M=64 edges/block, 256 threads = 4 waves, 32 KB LDS
// -> 4 blocks/CU (vs R4's 2): 4 independent phase streams interleave so the
// serial gather/barrier chain of one block hides under another's GEMMs.
// Each wave owns a DISJOINT 64-row hidden slice (4x64=256). Single in-place
// LDS buffer: Z tile -> H1 -> H2 (acc in AGPRs across each barrier).
// Address/swizzle math identical to the verified R4 kernel.
__global__ __launch_bounds__(256, 4) void edge_mlp_kernel(
    const uint16_t* __restrict__ zu, const uint16_t* __restrict__ zb,
    const int* __restrict__ eidx,
    const uint16_t* __restrict__ w1, const uint16_t* __restrict__ w2,
    const uint16_t* __restrict__ w3,
    const float* __restrict__ b1, const float* __restrict__ b2,
    const float* __restrict__ b3v,
    float* __restrict__ out)
{
  __shared__ __align__(16) unsigned char buf[32768];   // [64 edges][512 B], XOR-swizzled

  const int tid = (int)threadIdx.x;
  const int w  = tid >> 6;          // 0..3
  const int l  = tid & 63;
  const int lg = l >> 4;            // 0..3
  const int lc = l & 15;            // 0..15
  const int g_half = (l >> 4) & 1;  // gather: 0=user 1=book
  const int g_row  = l >> 5;        // gather: edge within pair
  const int e0 = (int)blockIdx.x * M_TILE;

  // ---- gather: 64 edges, [user 256B | book 256B] per 512-B row, swizzled source ----
  #pragma unroll
  for (int i = 0; i < 8; ++i) {
    const int eloc = w*16 + i*2 + g_row;
    const int eg = e0 + eloc;                          // exact tiling, no tail
    int ni = eidx[g_half ? (E_NUM + eg) : eg];
    ni = ni < 0 ? 0 : (ni >= NNODES ? NNODES - 1 : ni);
    const int cc = lc ^ (eloc & 7);                    // pre-swizzled source chunk
    const uint16_t* gp = (g_half ? zb : zu) + (size_t)ni*128 + cc*8;
    __builtin_amdgcn_global_load_lds((const __attribute__((address_space(1))) void*)gp,
        (__attribute__((address_space(3))) void*)(buf + (w*16 + i*2)*512), 16, 0, 0);
  }
  __syncthreads();   // drains vmcnt

  // B-fragment addressing (verified in R4): elem k of edge e at byte
  // e*512 + ((2k) ^ ((e&7)<<4)); decompose with bbase + ((k0^lc4)<<6).
  const int bbase = lc*512 + ((lg ^ (lc & 3)) << 4);
  const int lc4  = (lc >> 2) & 1;
  const int rb   = w*64 + lc;       // wave's hidden slice rows (+ht*16)

  f32x4 acc[4][4];

  // ================= GEMM1: H1^T = W1 * Z^T =================
  #pragma unroll
  for (int ht = 0; ht < 4; ++ht)
    #pragma unroll
    for (int ms = 0; ms < 4; ++ms) acc[ht][ms] = (f32x4){0.f,0.f,0.f,0.f};
  #pragma unroll
  for (int k0 = 0; k0 < 8; ++k0) {
    short8 af[4];
    #pragma unroll
    for (int ht = 0; ht < 4; ++ht)
      af[ht] = *reinterpret_cast<const short8*>(w1 + (size_t)(rb + ht*16)*256 + k0*32 + lg*8);
    const int ko = ((k0 ^ lc4) << 6);
    #pragma unroll
    for (int ms = 0; ms < 4; ++ms) {
      const short8 bf = *reinterpret_cast<const short8*>(buf + ms*8192 + bbase + ko);
      #pragma unroll
      for (int ht = 0; ht < 4; ++ht)
        acc[ht][ms] = __builtin_amdgcn_mfma_f32_16x16x32_bf16(af[ht], bf, acc[ht][ms], 0, 0, 0);
    }
  }
  __syncthreads();   // everyone done reading Z
  #pragma unroll
  for (int ht = 0; ht < 4; ++ht) {
    const float4 bb = *reinterpret_cast<const float4*>(b1 + w*64 + ht*16 + lg*4);
    const int colw = (w*128 + ht*32 + lg*8) ^ ((lc & 7) << 4);
    #pragma unroll
    for (int ms = 0; ms < 4; ++ms) {
      uint2 pk;
      pk.x = pkbf(fmaxf(acc[ht][ms][0] + bb.x, 0.f), fmaxf(acc[ht][ms][1] + bb.y, 0.f));
      pk.y = pkbf(fmaxf(acc[ht][ms][2] + bb.z, 0.f), fmaxf(acc[ht][ms][3] + bb.w, 0.f));
      *reinterpret_cast<uint2*>(buf + (ms*16 + lc)*512 + colw) = pk;
    }
  }
  __syncthreads();   // H1 ready

  // ================= GEMM2: H2^T = W2 * H1^T =================
  #pragma unroll
  for (int ht = 0; ht < 4; ++ht)
    #pragma unroll
    for (int ms = 0; ms < 4; ++ms) acc[ht][ms] = (f32x4){0.f,0.f,0.f,0.f};
  #pragma unroll
  for (int k0 = 0; k0 < 8; ++k0) {
    short8 af[4];
    #pragma unroll
    for (int ht = 0; ht < 4; ++ht)
      af[ht] = *reinterpret_cast<const short8*>(w2 + (size_t)(rb + ht*16)*256 + k0*32 + lg*8);
    const int ko = ((k0 ^ lc4) << 6);
    #pragma unroll
    for (int ms = 0; ms < 4; ++ms) {
      const short8 bf = *reinterpret_cast<const short8*>(buf + ms*8192 + bbase + ko);
      #pragma unroll
      for (int ht = 0; ht < 4; ++ht)
        acc[ht][ms] = __builtin_amdgcn_mfma_f32_16x16x32_bf16(af[ht], bf, acc[ht][ms], 0, 0, 0);
    }
  }
  __syncthreads();   // everyone done reading H1
  #pragma unroll
  for (int ht = 0; ht < 4; ++ht) {
    const float4 bb = *reinterpret_cast<const float4*>(b2 + w*64 + ht*16 + lg*4);
    const int colw = (w*128 + ht*32 + lg*8) ^ ((lc & 7) << 4);
    #pragma unroll
    for (int ms = 0; ms < 4; ++ms) {
      uint2 pk;
      pk.x = pkbf(fmaxf(acc[ht][ms][0] + bb.x, 0.f), fmaxf(acc[ht][ms][1] + bb.y, 0.f));
      pk.y = pkbf(fmaxf(acc[ht][ms][2] + bb.z, 0.f), fmaxf(acc[ht][ms][3] + bb.w, 0.f));
      *reinterpret_cast<uint2*>(buf + (ms*16 + lc)*512 + colw) = pk;
    }
  }
  __syncthreads();   // H2 ready

  // ====== GEMM3: O^T = W3pad * H2^T ; wave w owns edges [w*16, w*16+16) ======
  f32x4 acc3 = (f32x4){0.f,0.f,0.f,0.f};
  const int e3base = (w*16 + lc)*512 + ((lg ^ (lc & 3)) << 4);
  #pragma unroll
  for (int k0 = 0; k0 < 8; ++k0) {
    const short8 a3  = *reinterpret_cast<const short8*>(w3 + (size_t)lc*256 + k0*32 + lg*8);
    const short8 b3f = *reinterpret_cast<const short8*>(buf + e3base + ((k0 ^ lc4) << 6));
    acc3 = __builtin_amdgcn_mfma_f32_16x16x32_bf16(a3, b3f, acc3, 0, 0, 0);
  }

  // ---- log_softmax over n=0..9 ; lane holds n = lg*4 + r for its edge ----
  float vv[4];
  float mx = -3.0e38f;
  #pragma unroll
  for (int r = 0; r < 4; ++r) {
    const int n = lg*4 + r;
    const float x = acc3[r] + ((n < 10) ? b3v[n] : 0.f);
    vv[r] = x;
    if (n < 10) mx = fmaxf(mx, x);
  }
  mx = fmaxf(mx, __shfl_xor(mx, 16));
  mx = fmaxf(mx, __shfl_xor(mx, 32));
  float s = 0.f;
  #pragma unroll
  for (int r = 0; r < 4; ++r) {
    const int n = lg*4 + r;
    if (n < 10) s += __expf(vv[r] - mx);
  }
  s += __shfl_xor(s, 16);
  s += __shfl_xor(s, 32);
  const float lse = mx + __logf(s);

  const int e = e0 + w*16 + lc;
  float* po = out + (size_t)e*10;
  if (lg == 0) {
    *reinterpret_cast<float2*>(po)     = make_float2(vv[0] - lse, vv[1] - lse);
    *reinterpret_cast<float2*>(po + 2) = make_float2(vv[2] - lse, vv[3] - lse);
  } else if (lg == 1) {
    *reinterpret_cast<float2*>(po + 4) = make_float2(vv[0] - lse, vv[1] - lse);
    *reinterpret_cast<float2*>(po + 6) = make_float2(vv[2] - lse, vv[3] - lse);
  } else if (lg == 2) {
    *reinterpret_cast<float2*>(po + 8) = make_float2(vv[0] - lse, vv[1] - lse);
  }
}

extern "C" void kernel_launch(void* const* d_in, const int* in_sizes, int n_in,
                              void* d_out, int out_size, void* d_ws, size_t ws_size,
                              hipStream_t stream) {
  const float* z_user = (const float*)d_in[0];
  const float* z_book = (const float*)d_in[1];
  const int*   eidx   = (const int*)d_in[2];
  const float* W1     = (const float*)d_in[3];
  const float* b1     = (const float*)d_in[4];
  const float* W2     = (const float*)d_in[5];
  const float* b2     = (const float*)d_in[6];
  const float* W3     = (const float*)d_in[7];
  const float* b3     = (const float*)d_in[8];
  float* out = (float*)d_out;

  uint8_t* ws = (uint8_t*)d_ws;
  uint16_t* zu_b = (uint16_t*)(ws + OFF_ZU);
  uint16_t* zb_b = (uint16_t*)(ws + OFF_ZB);
  uint16_t* w1_b = (uint16_t*)(ws + OFF_W1);
  uint16_t* w2_b = (uint16_t*)(ws + OFF_W2);
  uint16_t* w3_b = (uint16_t*)(ws + OFF_W3);

  conv_z_kernel<<<2048, 256, 0, stream>>>(z_user, z_book, zu_b, zb_b);
  conv_w_kernel<<<256, 256, 0, stream>>>(W1, W2, W3, w1_b, w2_b, w3_b);
  edge_mlp_kernel<<<NBLK, 256, 0, stream>>>(zu_b, zb_b, eidx,
                                            w1_b, w2_b, w3_b,
                                            b1, b2, b3, out);
}

// Round 11
// 539.423 us; speedup vs baseline: 1.4436x; 1.4436x over previous
//
#include <hip/hip_runtime.h>
#include <stdint.h>

#define E_NUM 1000000
#define NNODES 100000
#define M_TILE 128
#define NBLK 7813   // ceil(1e6 / 128)

typedef __attribute__((ext_vector_type(8))) short short8;
typedef __attribute__((ext_vector_type(4))) short short4v;
typedef __attribute__((ext_vector_type(4))) float f32x4;
typedef __attribute__((ext_vector_type(16))) float f32x16;

// ws layout (bytes)
static constexpr size_t OFF_ZU = 0;                       // 100000*128*2 = 25,600,000
static constexpr size_t OFF_ZB = 25600000;                // + 25,600,000
static constexpr size_t OFF_W1 = 51200000;                // 256*256*2 = 131072
static constexpr size_t OFF_W2 = 51200000 + 131072;
static constexpr size_t OFF_W3 = 51200000 + 262144;       // padded [16][256] bf16 = 8192

__device__ __forceinline__ uint16_t f2bf(float x) {
  union { float f; uint32_t u; } a; a.f = x;
  uint32_t r = a.u + 0x7fffu + ((a.u >> 16) & 1u);  // round-to-nearest-even
  return (uint16_t)(r >> 16);
}

__device__ __forceinline__ uint32_t pkbf(float a, float b) {
  uint32_t r;
  asm("v_cvt_pk_bf16_f32 %0, %1, %2" : "=v"(r) : "v"(a), "v"(b));
  return r;
}

__global__ void conv_z_kernel(const float* __restrict__ zu, const float* __restrict__ zb,
                              uint16_t* __restrict__ ou, uint16_t* __restrict__ ob) {
  const int64_t n4 = (int64_t)NNODES * 128 / 4;
  for (int64_t i = (int64_t)blockIdx.x * blockDim.x + threadIdx.x; i < n4;
       i += (int64_t)gridDim.x * blockDim.x) {
    float4 u = reinterpret_cast<const float4*>(zu)[i];
    float4 b = reinterpret_cast<const float4*>(zb)[i];
    short4v pu, pb;
    pu[0] = (short)f2bf(u.x); pu[1] = (short)f2bf(u.y);
    pu[2] = (short)f2bf(u.z); pu[3] = (short)f2bf(u.w);
    pb[0] = (short)f2bf(b.x); pb[1] = (short)f2bf(b.y);
    pb[2] = (short)f2bf(b.z); pb[3] = (short)f2bf(b.w);
    *reinterpret_cast<short4v*>(ou + i * 4) = pu;
    *reinterpret_cast<short4v*>(ob + i * 4) = pb;
  }
}

__global__ void conv_w_kernel(const float* __restrict__ W1, const float* __restrict__ W2,
                              const float* __restrict__ W3,
                              uint16_t* __restrict__ o1, uint16_t* __restrict__ o2,
                              uint16_t* __restrict__ o3) {
  const int i = blockIdx.x * 256 + threadIdx.x;
  if (i < 65536) {
    o1[i] = f2bf(W1[i]);
    o2[i] = f2bf(W2[i]);
  }
  if (i < 4096) {  // W3 padded [10][256] -> [16][256], zero rows
    const int r = i >> 8, c = i & 255;
    o3[i] = (r < 10) ? f2bf(W3[r * 256 + c]) : (uint16_t)0;
  }
}

// R4 structure (M=128, 8 waves, single in-place 64KB LDS, non-persistent —
// measured 424us, FETCH 245MB) with GEMM1/2 moved to mfma_32x32x16_bf16:
// half the MFMA instructions and ~half the live A-regs -> compiler headroom
// for load pipelining under the hard 128-reg/wave budget (2 blocks/CU).
// Layouts: A/B lane = row|col (lane&31), k-off (lane>>5)*8; C: col=lane&31,
// row=(reg&3)+8*(reg>>2)+4*(lane>>5).  GEMM3/softmax/gather identical to R4.
__global__ __launch_bounds__(512, 4) void edge_mlp_kernel(
    const uint16_t* __restrict__ zu, const uint16_t* __restrict__ zb,
    const int* __restrict__ eidx,
    const uint16_t* __restrict__ w1, const uint16_t* __restrict__ w2,
    const uint16_t* __restrict__ w3,
    const float* __restrict__ b1, const float* __restrict__ b2,
    const float* __restrict__ b3v,
    float* __restrict__ out)
{
  __shared__ __align__(16) unsigned char buf[65536];   // [128 edges][512 B], XOR-swizzled

  const int tid = (int)threadIdx.x;
  const int w  = tid >> 6;          // 0..7
  const int l  = tid & 63;
  const int lg = l >> 4;            // 0..3  (16x16 path, GEMM3)
  const int lc = l & 15;            // 0..15 (16x16 path, GEMM3)
  const int l31 = l & 31;           // 32x32 path
  const int hi  = l >> 5;           // 32x32 path
  const int g_half = (l >> 4) & 1;  // gather: 0=user 1=book
  const int g_row  = l >> 5;        // gather: edge within pair
  const int e0 = (int)blockIdx.x * M_TILE;

  // ---- gather: 128 edges, [user 256B | book 256B] per 512-B row, swizzled source ----
  #pragma unroll
  for (int i = 0; i < 8; ++i) {
    const int eloc = w*16 + i*2 + g_row;
    int eg = e0 + eloc; if (eg >= E_NUM) eg = E_NUM - 1;
    int ni = eidx[g_half ? (E_NUM + eg) : eg];
    ni = ni < 0 ? 0 : (ni >= NNODES ? NNODES - 1 : ni);
    const int cc = lc ^ (eloc & 7);                    // pre-swizzled source chunk
    const uint16_t* gp = (g_half ? zb : zu) + (size_t)ni*128 + cc*8;
    __builtin_amdgcn_global_load_lds((const __attribute__((address_space(1))) void*)gp,
        (__attribute__((address_space(3))) void*)(buf + (w*16 + i*2)*512), 16, 0, 0);
  }
  __syncthreads();   // drains vmcnt

  // 32x32 B addressing: edge = ms*32 + l31; chunk bytes (kstep*32 + hi*16),
  // XOR ((edge&7)<<4) with edge&7 == l31&7.  (k<<5)|(hi<<4) disjoint bits ->
  // addr = (ms*32+l31)*512 + ((kstep*32) ^ xk),  xk = (hi*16) ^ ((l31&7)<<4).
  const int bswz = (l31 & 7) << 4;
  const int xk   = (hi << 4) ^ bswz;
  const int arow = w*32 + l31;       // wave's 32 hidden rows (A operand row)

  f32x16 acc32[4];

  // ================= GEMM1: H1^T = W1 * Z^T (32x32x16) =================
  #pragma unroll
  for (int ms = 0; ms < 4; ++ms)
    acc32[ms] = (f32x16){0.f,0.f,0.f,0.f,0.f,0.f,0.f,0.f,0.f,0.f,0.f,0.f,0.f,0.f,0.f,0.f};
  #pragma unroll
  for (int ks = 0; ks < 16; ++ks) {
    const short8 af = *reinterpret_cast<const short8*>(w1 + (size_t)arow*256 + ks*16 + hi*8);
    const int ko = (ks*32) ^ xk;
    short8 bf[4];
    #pragma unroll
    for (int ms = 0; ms < 4; ++ms)
      bf[ms] = *reinterpret_cast<const short8*>(buf + (ms*32 + l31)*512 + ko);
    __builtin_amdgcn_s_setprio(1);
    #pragma unroll
    for (int ms = 0; ms < 4; ++ms)
      acc32[ms] = __builtin_amdgcn_mfma_f32_32x32x16_bf16(af, bf[ms], acc32[ms], 0, 0, 0);
    __builtin_amdgcn_s_setprio(0);
  }
  __syncthreads();   // everyone done reading Z
  // epilogue1: bias+relu+pack -> H1 in place. lane: edge=ms*32+l31;
  // rows hb = w*32 + 8q + 4hi + {0..3} from regs 4q..4q+3.
  #pragma unroll
  for (int q = 0; q < 4; ++q) {
    const float4 bb = *reinterpret_cast<const float4*>(b1 + w*32 + q*8 + hi*4);
    const int colw = (w*64 + q*16 + hi*8) ^ bswz;
    #pragma unroll
    for (int ms = 0; ms < 4; ++ms) {
      uint2 pk;
      pk.x = pkbf(fmaxf(acc32[ms][4*q+0] + bb.x, 0.f), fmaxf(acc32[ms][4*q+1] + bb.y, 0.f));
      pk.y = pkbf(fmaxf(acc32[ms][4*q+2] + bb.z, 0.f), fmaxf(acc32[ms][4*q+3] + bb.w, 0.f));
      *reinterpret_cast<uint2*>(buf + (ms*32 + l31)*512 + colw) = pk;
    }
  }
  __syncthreads();   // H1 ready

  // ================= GEMM2: H2^T = W2 * H1^T (32x32x16) =================
  #pragma unroll
  for (int ms = 0; ms < 4; ++ms)
    acc32[ms] = (f32x16){0.f,0.f,0.f,0.f,0.f,0.f,0.f,0.f,0.f,0.f,0.f,0.f,0.f,0.f,0.f,0.f};
  #pragma unroll
  for (int ks = 0; ks < 16; ++ks) {
    const short8 af = *reinterpret_cast<const short8*>(w2 + (size_t)arow*256 + ks*16 + hi*8);
    const int ko = (ks*32) ^ xk;
    short8 bf[4];
    #pragma unroll
    for (int ms = 0; ms < 4; ++ms)
      bf[ms] = *reinterpret_cast<const short8*>(buf + (ms*32 + l31)*512 + ko);
    __builtin_amdgcn_s_setprio(1);
    #pragma unroll
    for (int ms = 0; ms < 4; ++ms)
      acc32[ms] = __builtin_amdgcn_mfma_f32_32x32x16_bf16(af, bf[ms], acc32[ms], 0, 0, 0);
    __builtin_amdgcn_s_setprio(0);
  }
  __syncthreads();   // everyone done reading H1
  #pragma unroll
  for (int q = 0; q < 4; ++q) {
    const float4 bb = *reinterpret_cast<const float4*>(b2 + w*32 + q*8 + hi*4);
    const int colw = (w*64 + q*16 + hi*8) ^ bswz;
    #pragma unroll
    for (int ms = 0; ms < 4; ++ms) {
      uint2 pk;
      pk.x = pkbf(fmaxf(acc32[ms][4*q+0] + bb.x, 0.f), fmaxf(acc32[ms][4*q+1] + bb.y, 0.f));
      pk.y = pkbf(fmaxf(acc32[ms][4*q+2] + bb.z, 0.f), fmaxf(acc32[ms][4*q+3] + bb.w, 0.f));
      *reinterpret_cast<uint2*>(buf + (ms*32 + l31)*512 + colw) = pk;
    }
  }
  __syncthreads();   // H2 ready

  // ====== GEMM3: O^T = W3pad * H2^T (16x16x32, unchanged from R4) ======
  f32x4 acc3 = (f32x4){0.f,0.f,0.f,0.f};
  const int lc4 = (lc >> 2) & 1;
  const int e3base = (w*16 + lc)*512 + ((lg ^ (lc & 3)) << 4);
  #pragma unroll
  for (int k0 = 0; k0 < 8; ++k0) {
    const short8 a3  = *reinterpret_cast<const short8*>(w3 + (size_t)lc*256 + k0*32 + lg*8);
    const short8 b3f = *reinterpret_cast<const short8*>(buf + e3base + ((k0 ^ lc4) << 6));
    acc3 = __builtin_amdgcn_mfma_f32_16x16x32_bf16(a3, b3f, acc3, 0, 0, 0);
  }

  // ---- log_softmax over n=0..9 ; lane holds n = lg*4 + r for its edge ----
  float vv[4];
  float mx = -3.0e38f;
  #pragma unroll
  for (int r = 0; r < 4; ++r) {
    const int n = lg*4 + r;
    const float x = acc3[r] + ((n < 10) ? b3v[n] : 0.f);
    vv[r] = x;
    if (n < 10) mx = fmaxf(mx, x);
  }
  mx = fmaxf(mx, __shfl_xor(mx, 16));
  mx = fmaxf(mx, __shfl_xor(mx, 32));
  float s = 0.f;
  #pragma unroll
  for (int r = 0; r < 4; ++r) {
    const int n = lg*4 + r;
    if (n < 10) s += __expf(vv[r] - mx);
  }
  s += __shfl_xor(s, 16);
  s += __shfl_xor(s, 32);
  const float lse = mx + __logf(s);

  const int e = e0 + w*16 + lc;
  if (e < E_NUM) {
    float* po = out + (size_t)e*10;
    if (lg == 0) {
      *reinterpret_cast<float2*>(po)     = make_float2(vv[0] - lse, vv[1] - lse);
      *reinterpret_cast<float2*>(po + 2) = make_float2(vv[2] - lse, vv[3] - lse);
    } else if (lg == 1) {
      *reinterpret_cast<float2*>(po + 4) = make_float2(vv[0] - lse, vv[1] - lse);
      *reinterpret_cast<float2*>(po + 6) = make_float2(vv[2] - lse, vv[3] - lse);
    } else if (lg == 2) {
      *reinterpret_cast<float2*>(po + 8) = make_float2(vv[0] - lse, vv[1] - lse);
    }
  }
}

extern "C" void kernel_launch(void* const* d_in, const int* in_sizes, int n_in,
                              void* d_out, int out_size, void* d_ws, size_t ws_size,
                              hipStream_t stream) {
  const float* z_user = (const float*)d_in[0];
  const float* z_book = (const float*)d_in[1];
  const int*   eidx   = (const int*)d_in[2];
  const float* W1     = (const float*)d_in[3];
  const float* b1     = (const float*)d_in[4];
  const float* W2     = (const float*)d_in[5];
  const float* b2     = (const float*)d_in[6];
  const float* W3     = (const float*)d_in[7];
  const float* b3     = (const float*)d_in[8];
  float* out = (float*)d_out;

  uint8_t* ws = (uint8_t*)d_ws;
  uint16_t* zu_b = (uint16_t*)(ws + OFF_ZU);
  uint16_t* zb_b = (uint16_t*)(ws + OFF_ZB);
  uint16_t* w1_b = (uint16_t*)(ws + OFF_W1);
  uint16_t* w2_b = (uint16_t*)(ws + OFF_W2);
  uint16_t* w3_b = (uint16_t*)(ws + OFF_W3);

  conv_z_kernel<<<2048, 256, 0, stream>>>(z_user, z_book, zu_b, zb_b);
  conv_w_kernel<<<256, 256, 0, stream>>>(W1, W2, W3, w1_b, w2_b, w3_b);
  edge_mlp_kernel<<<NBLK, 512, 0, stream>>>(zu_b, zb_b, eidx,
                                            w1_b, w2_b, w3_b,
                                            b1, b2, b3, out);
}